// Round 7
// baseline (434.335 us; speedup 1.0000x reference)
//
#include <hip/hip_runtime.h>

// ---------------------------------------------------------------------------
// R12: (a) pack_all REVERTED to R10 exactly (84 µs best; R11's reg-direct Xp1
// scattered 16B stores -> WRITE_SIZE 139->170 MB, +13 µs. The LDS round-trip
// is the write-coalescing stage — keep it).
// (b) NEW: gemm1/gemm2p grid permute so mt varies FASTEST: the 4 mt-blocks
// sharing one 256 KB B-slab become dispatch-adjacent -> co-resident -> slab
// fetched once, 3 reads L2/L3-hot (T1 mechanism via dispatch order).
// Pure index remap, correctness-identical.
// ---------------------------------------------------------------------------

typedef float    f32x4  __attribute__((ext_vector_type(4)));
typedef __bf16   bf16x8 __attribute__((ext_vector_type(8)));
typedef unsigned u32x4  __attribute__((ext_vector_type(4)));

__device__ __forceinline__ ushort f2b(float x) {
  union { float f; unsigned u; } v; v.f = x;
  unsigned r = (v.u + 0x7fffu + ((v.u >> 16) & 1u)) >> 16;
  return (ushort)r;
}
__device__ __forceinline__ float b2f(ushort h) {
  union { unsigned u; float f; } v; v.u = ((unsigned)h) << 16; return v.f;
}
__device__ __forceinline__ void unpack2(unsigned v, float& lo, float& hi) {
  union { unsigned u; float f; } a, b;
  a.u = v << 16; b.u = v & 0xffff0000u;
  lo = a.f; hi = b.f;
}
__device__ __forceinline__ unsigned packb(float a, float b) {
  return (unsigned)f2b(a) | ((unsigned)f2b(b) << 16);
}
__device__ __forceinline__ int swz(int r) { return (r & 3) ^ ((r >> 2) & 3); }

__device__ __forceinline__ void gload16(const void* g, void* l) {
  __builtin_amdgcn_global_load_lds(
      (const __attribute__((address_space(1))) void*)g,
      (__attribute__((address_space(3))) void*)l, 16, 0, 0);
}

// ---------------------------------------------------------------------------
// pack_all: z<8 -> pack X tile into Xp1/Xp2 (R5 logic); z in {8,9} -> pack
// one 64x64 weight tile. grid (16, 32, 10), 256 thr. [R10 verbatim]
// ---------------------------------------------------------------------------
__global__ __launch_bounds__(256) void pack_all(
    const float* __restrict__ X, ushort* __restrict__ Xp1, ushort* __restrict__ Xp2,
    const float* __restrict__ Wq, const float* __restrict__ Wk,
    const float* __restrict__ Wv, const float* __restrict__ Wo,
    ushort* __restrict__ WqT, ushort* __restrict__ Wkb,
    ushort* __restrict__ WvT, ushort* __restrict__ WoT) {
  const int t = threadIdx.x;
  if (blockIdx.z < 8) {
    const int z = blockIdx.z, jb = blockIdx.y, cb = blockIdx.x;
    __shared__ ushort sT[128 * 72];
#pragma unroll
    for (int rep = 0; rep < 2; ++rep) {
      const int j  = rep * 64 + (t >> 2);
      const int c0 = (t & 3) << 4;
      const float4* src = (const float4*)(X + ((size_t)z * 4096 + jb * 128 + j) * 1024 + cb * 64 + c0);
#pragma unroll
      for (int q = 0; q < 4; ++q) {
        const float4 v = src[q];
        ushort4 w; w.x = f2b(v.x); w.y = f2b(v.y); w.z = f2b(v.z); w.w = f2b(v.w);
        *(ushort4*)&sT[j * 72 + c0 + q * 4] = w;
      }
    }
    __syncthreads();

    ushort* o1 = Xp1 + ((size_t)(z * 32 + jb) * 32 + cb * 2) * 4096;
#pragma unroll
    for (int q = 0; q < 4; ++q) {
      const int kih = q >> 1;
      const int r   = ((q & 1) << 6) + (t >> 2);
      const int p   = t & 3;
      const int lc  = p ^ swz(r);
      const u32x4 v = *(const u32x4*)&sT[r * 72 + kih * 32 + lc * 8];
      __builtin_nontemporal_store(
          v, (u32x4*)&o1[(size_t)kih * 4096 + ((size_t)(q & 1) << 11) + (size_t)t * 8]);
    }

    ushort* o2 = Xp2 + (((size_t)(z * 8 + (cb >> 1)) * 128 + jb * 4) * 4096) + ((size_t)(cb & 1) << 11);
#pragma unroll
    for (int q = 0; q < 4; ++q) {
      const int cl = t >> 2;
      const int p2 = t & 3;
      const int lj = p2 ^ swz(cl);
      union { ushort u[8]; u32x4 v; } pk;
#pragma unroll
      for (int jj = 0; jj < 8; ++jj) pk.u[jj] = sT[(q * 32 + lj * 8 + jj) * 72 + cl];
      __builtin_nontemporal_store(
          pk.v, (u32x4*)&o2[(size_t)q * 4096 + (size_t)t * 8]);
    }
  } else {
    const int wsel = (blockIdx.z - 8) * 2 + (blockIdx.y >> 4);
    const float* src = (wsel == 0) ? Wq : (wsel == 1) ? Wk : (wsel == 2) ? Wv : Wo;
    const int row0 = (blockIdx.y & 15) << 6, col0 = blockIdx.x << 6;
    __shared__ ushort sW[64 * 72];
    const int r = t >> 2, c0 = (t & 3) << 4;

    union { ushort u[16]; uint4 v[2]; } pk;
    const float4* s4 = (const float4*)(src + (size_t)(row0 + r) * 1024 + col0 + c0);
#pragma unroll
    for (int q = 0; q < 4; ++q) {
      const float4 v = s4[q];
      pk.u[q*4+0] = f2b(v.x); pk.u[q*4+1] = f2b(v.y);
      pk.u[q*4+2] = f2b(v.z); pk.u[q*4+3] = f2b(v.w);
    }
    if (wsel == 1) {
      ushort* dst = Wkb + (size_t)(row0 + r) * 1024 + col0 + c0;
      *(uint4*)dst = pk.v[0];
      *(uint4*)(dst + 8) = pk.v[1];
    } else {
#pragma unroll
      for (int q = 0; q < 16; ++q) sW[r * 72 + c0 + q] = pk.u[q];
      __syncthreads();
      ushort* dst = (wsel == 0) ? WqT : (wsel == 2) ? WvT : WoT;
      union { ushort u[16]; uint4 v[2]; } o;
#pragma unroll
      for (int q = 0; q < 16; ++q) o.u[q] = sW[(c0 + q) * 72 + r];
      ushort* d = dst + (size_t)(col0 + r) * 1024 + row0 + c0;
      *(uint4*)d = o.v[0];
      *(uint4*)(d + 8) = o.v[1];
    }
  }
}

// ---------------------------------------------------------------------------
// qrope_gemm: q = hs @ Wq, K-split x4 -> qP fp32 [4][256][1024]. grid (8,2,4).
// ---------------------------------------------------------------------------
__global__ __launch_bounds__(256) void qrope_gemm(
    const float* __restrict__ hs, const ushort* __restrict__ WqT,
    float* __restrict__ qP) {
  __shared__ alignas(16) ushort sA[128 * 40];
  __shared__ alignas(16) ushort sB[128 * 40];
  const int nt = blockIdx.x, mt = blockIdx.y, ks = blockIdx.z;
  const int m0 = mt << 7, n0 = nt << 7, kb = ks << 8;
  const int t = threadIdx.x;
  const int wave = t >> 6, lane = t & 63;
  const int wm = wave >> 1, wn = wave & 1;
  const int fr = lane & 15, fq = lane >> 4;
  const int r = t >> 1, sg = (t & 1) << 4;

  f32x4 acc[4][4];
#pragma unroll
  for (int a = 0; a < 4; ++a)
#pragma unroll
    for (int c = 0; c < 4; ++c) acc[a][c] = (f32x4){0.f, 0.f, 0.f, 0.f};

  for (int it = 0; it < 8; ++it) {
    const int k0 = kb + (it << 5);
    {
      const float4* s4 = (const float4*)(hs + (size_t)(m0 + r) * 1024 + k0 + sg);
      union { ushort u[16]; uint4 v[2]; } pk;
#pragma unroll
      for (int q = 0; q < 4; ++q) {
        const float4 v = s4[q];
        pk.u[q*4+0] = f2b(v.x); pk.u[q*4+1] = f2b(v.y);
        pk.u[q*4+2] = f2b(v.z); pk.u[q*4+3] = f2b(v.w);
      }
      *(uint4*)&sA[r * 40 + sg]     = pk.v[0];
      *(uint4*)&sA[r * 40 + sg + 8] = pk.v[1];
    }
    {
      const uint4* s4 = (const uint4*)(WqT + (size_t)(n0 + r) * 1024 + k0 + sg);
      *(uint4*)&sB[r * 40 + sg]     = s4[0];
      *(uint4*)&sB[r * 40 + sg + 8] = s4[1];
    }
    __syncthreads();
    bf16x8 aF[4], bF[4];
#pragma unroll
    for (int u = 0; u < 4; ++u) {
      aF[u] = *(const bf16x8*)&sA[((wm << 6) + (u << 4) + fr) * 40 + (fq << 3)];
      bF[u] = *(const bf16x8*)&sB[((wn << 6) + (u << 4) + fr) * 40 + (fq << 3)];
    }
#pragma unroll
    for (int mi = 0; mi < 4; ++mi)
#pragma unroll
      for (int ni = 0; ni < 4; ++ni)
        acc[mi][ni] = __builtin_amdgcn_mfma_f32_16x16x32_bf16(
            aF[mi], bF[ni], acc[mi][ni], 0, 0, 0);
    __syncthreads();
  }
  float* dst = qP + (size_t)ks * 262144;
#pragma unroll
  for (int mi = 0; mi < 4; ++mi)
#pragma unroll
    for (int ni = 0; ni < 4; ++ni)
#pragma unroll
      for (int rr = 0; rr < 4; ++rr) {
        const int row = m0 + (wm << 6) + (mi << 4) + (fq << 2) + rr;
        const int col = n0 + (wn << 6) + (ni << 4) + fr;
        dst[(size_t)row * 1024 + col] = acc[mi][ni][rr];
      }
}

// ---------------------------------------------------------------------------
// qk_rope_gemm: sA = bf16(RoPE(sum_ks qP)*0.125); qk = sA @ Wkb_head^T.
// grid (4 nc, 16 h, 8 b).
// ---------------------------------------------------------------------------
__global__ __launch_bounds__(256) void qk_rope_gemm(
    const float* __restrict__ qP, const ushort* __restrict__ Wkb,
    const int* __restrict__ pos, ushort* __restrict__ qk) {
  __shared__ float s_qf[32 * 68];
  __shared__ alignas(16) ushort sA[32 * 72];
  __shared__ alignas(16) ushort sB[256 * 72];
  const int nc = blockIdx.x, h = blockIdx.y, b = blockIdx.z;
  const int t = threadIdx.x;
  const int i = t >> 3, d0 = (t & 7) << 3;

  {
    float s[8];
#pragma unroll
    for (int j = 0; j < 8; ++j) s[j] = 0.f;
#pragma unroll
    for (int p = 0; p < 4; ++p) {
      const float* base = qP + (size_t)p * 262144 + (size_t)(b * 32 + i) * 1024 + h * 64 + d0;
      const float4 a0 = *(const float4*)base;
      const float4 a1 = *(const float4*)(base + 4);
      s[0]+=a0.x; s[1]+=a0.y; s[2]+=a0.z; s[3]+=a0.w;
      s[4]+=a1.x; s[5]+=a1.y; s[6]+=a1.z; s[7]+=a1.w;
    }
#pragma unroll
    for (int j = 0; j < 8; ++j) s_qf[i * 68 + d0 + j] = s[j];
  }
#pragma unroll
  for (int p = 0; p < 8; ++p) {
    const int rr = (t >> 3) + p * 32, seg = (t & 7) << 3;
    *(uint4*)&sB[rr * 72 + seg] =
        *(const uint4*)(Wkb + (size_t)(nc * 256 + rr) * 1024 + h * 64 + seg);
  }
  __syncthreads();

  {
    // int64 vs int32 layout probe: 16 odd slots suffice (P(all-zero|int32)~0)
    unsigned oddor = 0;
#pragma unroll
    for (int j = 1; j < 32; j += 2) oddor |= (unsigned)pos[j];
    const int m = b * 32 + i;
    const int p = (oddor == 0) ? pos[2 * m] : pos[m];
    const float pf = (float)p;
    union { ushort u16[8]; uint4 v; } o;
#pragma unroll
    for (int j = 0; j < 8; ++j) {
      const int d = d0 + j;
      const int f = d & 31;
      const float inv = powf(10000.0f, -(float)f * (1.0f / 32.0f));
      float sn, cs; sincosf(pf * inv, &sn, &cs);
      const float x  = s_qf[i * 68 + d];
      const float xp = s_qf[i * 68 + (d ^ 32)];
      const float v  = (d < 32) ? (x * cs - xp * sn) : (x * cs + xp * sn);
      o.u16[j] = f2b(v * 0.125f);
    }
    *(uint4*)&sA[i * 72 + d0] = o.v;
  }
  __syncthreads();

  const int wave = t >> 6, lane = t & 63;
  const int fr = lane & 15, fq = lane >> 4;
  f32x4 acc[2][4];
#pragma unroll
  for (int a = 0; a < 2; ++a)
#pragma unroll
    for (int c = 0; c < 4; ++c) acc[a][c] = (f32x4){0.f, 0.f, 0.f, 0.f};

#pragma unroll
  for (int ki = 0; ki < 2; ++ki) {
    bf16x8 aF[2], bF[4];
#pragma unroll
    for (int mi = 0; mi < 2; ++mi)
      aF[mi] = *(const bf16x8*)&sA[((mi << 4) + fr) * 72 + (ki << 5) + (fq << 3)];
#pragma unroll
    for (int ni = 0; ni < 4; ++ni)
      bF[ni] = *(const bf16x8*)&sB[((wave << 6) + (ni << 4) + fr) * 72 + (ki << 5) + (fq << 3)];
#pragma unroll
    for (int mi = 0; mi < 2; ++mi)
#pragma unroll
      for (int ni = 0; ni < 4; ++ni)
        acc[mi][ni] = __builtin_amdgcn_mfma_f32_16x16x32_bf16(
            aF[mi], bF[ni], acc[mi][ni], 0, 0, 0);
  }
#pragma unroll
  for (int mi = 0; mi < 2; ++mi)
#pragma unroll
    for (int ni = 0; ni < 4; ++ni)
#pragma unroll
      for (int rr = 0; rr < 4; ++rr) {
        const int row = h * 32 + (mi << 4) + (fq << 2) + rr;
        const int col = nc * 256 + (wave << 6) + (ni << 4) + fr;
        qk[((size_t)b * 512 + row) * 1024 + col] = f2b(acc[mi][ni][rr]);
      }
}

// ---------------------------------------------------------------------------
// G1: scores = qk @ X^T, BK=64. Packed Sc + per-row (max,sumexp) partials.
// grid (4 mt, 8 z, 32 nty) — mt FASTEST so the 4 blocks sharing one B-slab
// are dispatch-adjacent (slab fetched once, 3 reads cache-hot).
// ---------------------------------------------------------------------------
__global__ __launch_bounds__(256) void gemm1(
    const ushort* __restrict__ qk, const ushort* __restrict__ Xp1,
    ushort* __restrict__ Sc, float2* __restrict__ pstat) {
  __shared__ alignas(16) ushort sA[8192];
  __shared__ alignas(16) ushort sB[8192];
  __shared__ float sMx[256], sSm[256];
  const int mt = blockIdx.x, z = blockIdx.y, nty = blockIdx.z;
  const int tid = threadIdx.x;
  const int wave = tid >> 6, lane = tid & 63;
  const int wm = wave >> 1, wn = wave & 1;
  const int fr = lane & 15, fq = lane >> 4;
  const int sfr = swz(fr);

  const ushort* Ab = qk + ((size_t)z * 512 + mt * 128) * 1024;
  const ushort* Bb = Xp1 + ((size_t)(z * 32 + nty) * 32) * 4096;

  int arow[4], aoff[4];
#pragma unroll
  for (int j = 0; j < 4; ++j) {
    const int rowA = ((wave & 1) << 6) + (j << 4) + (lane >> 2);
    arow[j] = rowA;
    aoff[j] = ((wave >> 1) << 5) + (((lane & 3) ^ swz(rowA)) << 3);
  }

  f32x4 acc[4][4];
#pragma unroll
  for (int a = 0; a < 4; ++a)
#pragma unroll
    for (int c = 0; c < 4; ++c) acc[a][c] = (f32x4){0.f, 0.f, 0.f, 0.f};

  for (int it = 0; it < 16; ++it) {
    const int k0 = it << 6;
#pragma unroll
    for (int j = 0; j < 4; ++j) {
      gload16(Bb + (size_t)it * 8192 + wave * 2048 + j * 512 + lane * 8,
              &sB[wave * 2048 + j * 512]);
      gload16(Ab + (size_t)arow[j] * 1024 + k0 + aoff[j],
              &sA[wave * 2048 + j * 512]);
    }
    __syncthreads();
#pragma unroll
    for (int kk = 0; kk < 2; ++kk) {
      bf16x8 aF[4], bF[4];
#pragma unroll
      for (int u = 0; u < 4; ++u) {
        aF[u] = *(const bf16x8*)&sA[kk * 4096 + ((wm << 6) + (u << 4) + fr) * 32 + ((fq ^ sfr) << 3)];
        bF[u] = *(const bf16x8*)&sB[kk * 4096 + ((wn << 6) + (u << 4) + fr) * 32 + ((fq ^ sfr) << 3)];
      }
#pragma unroll
      for (int mi = 0; mi < 4; ++mi)
#pragma unroll
        for (int ni = 0; ni < 4; ++ni)
          acc[mi][ni] = __builtin_amdgcn_mfma_f32_16x16x32_bf16(
              aF[mi], bF[ni], acc[mi][ni], 0, 0, 0);
    }
    __syncthreads();
  }

  ushort* ScB = Sc + (size_t)(z * 4 + mt) * 524288;
#pragma unroll
  for (int mi = 0; mi < 4; ++mi)
#pragma unroll
    for (int ni = 0; ni < 4; ++ni)
#pragma unroll
      for (int r = 0; r < 4; ++r) {
        const int row = (wm << 6) + (mi << 4) + (fq << 2) + r;
        const int col = (wn << 6) + (ni << 4) + fr;
        const int ki  = (nty << 2) + (col >> 5);
        const int p   = ((col >> 3) & 3) ^ r ^ fq;
        const ushort hb = f2b(acc[mi][ni][r]);
        ScB[(size_t)ki * 4096 + row * 32 + p * 8 + (fr & 7)] = hb;
        acc[mi][ni][r] = b2f(hb);
      }

#pragma unroll
  for (int mi = 0; mi < 4; ++mi)
#pragma unroll
    for (int r = 0; r < 4; ++r) {
      float m4 = fmaxf(fmaxf(acc[mi][0][r], acc[mi][1][r]),
                       fmaxf(acc[mi][2][r], acc[mi][3][r]));
#pragma unroll
      for (int o = 1; o < 16; o <<= 1) m4 = fmaxf(m4, __shfl_xor(m4, o));
      float s4 = __expf(acc[mi][0][r] - m4) + __expf(acc[mi][1][r] - m4) +
                 __expf(acc[mi][2][r] - m4) + __expf(acc[mi][3][r] - m4);
#pragma unroll
      for (int o = 1; o < 16; o <<= 1) s4 += __shfl_xor(s4, o);
      if (fr == 0) {
        const int row = (wm << 6) + (mi << 4) + (fq << 2) + r;
        sMx[row * 2 + wn] = m4;
        sSm[row * 2 + wn] = s4;
      }
    }
  __syncthreads();
  if (tid < 128) {
    const float m0 = sMx[tid * 2], m1 = sMx[tid * 2 + 1];
    const float M = fmaxf(m0, m1);
    const float S = sSm[tid * 2] * __expf(m0 - M) + sSm[tid * 2 + 1] * __expf(m1 - M);
    pstat[((size_t)(z * 512 + mt * 128 + tid)) * 32 + nty] = make_float2(M, S);
  }
}

// ---------------------------------------------------------------------------
// softmax_apply2: combine stats (prologue) + apply exp in place on packed Sc.
// grid (32 zmt, 16 kg), 256 thr; each block: 8 ki-slabs of 8KB.
// ---------------------------------------------------------------------------
__global__ __launch_bounds__(256) void softmax_apply2(
    ushort* __restrict__ Sc, const float2* __restrict__ pstat) {
  __shared__ float sM[128], sI[128];
  const int zmt = blockIdx.x, kg = blockIdx.y;
  const int t = threadIdx.x;
  if (t < 128) {
    const float2* p = pstat + ((size_t)zmt * 128 + t) * 32;
    float M = -1e30f;
#pragma unroll
    for (int i = 0; i < 32; ++i) M = fmaxf(M, p[i].x);
    float S = 0.f;
#pragma unroll
    for (int i = 0; i < 32; ++i) S += p[i].y * __expf(p[i].x - M);
    sM[t] = M; sI[t] = 1.0f / S;
  }
  __syncthreads();
  const int r = t >> 1;
  const float M = sM[r], inv = sI[r];
  ushort* base = Sc + ((size_t)zmt * 128 + kg * 8) * 4096 + t * 16;
#pragma unroll
  for (int kt = 0; kt < 8; ++kt) {
    uint4 v0 = *(uint4*)base;
    uint4 v1 = *(uint4*)(base + 8);
    float x0,x1,x2,x3,x4,x5,x6,x7;
    unpack2(v0.x, x0, x1); unpack2(v0.y, x2, x3);
    unpack2(v0.z, x4, x5); unpack2(v0.w, x6, x7);
    v0.x = packb(__expf(x0 - M) * inv, __expf(x1 - M) * inv);
    v0.y = packb(__expf(x2 - M) * inv, __expf(x3 - M) * inv);
    v0.z = packb(__expf(x4 - M) * inv, __expf(x5 - M) * inv);
    v0.w = packb(__expf(x6 - M) * inv, __expf(x7 - M) * inv);
    unpack2(v1.x, x0, x1); unpack2(v1.y, x2, x3);
    unpack2(v1.z, x4, x5); unpack2(v1.w, x6, x7);
    v1.x = packb(__expf(x0 - M) * inv, __expf(x1 - M) * inv);
    v1.y = packb(__expf(x2 - M) * inv, __expf(x3 - M) * inv);
    v1.z = packb(__expf(x4 - M) * inv, __expf(x5 - M) * inv);
    v1.w = packb(__expf(x6 - M) * inv, __expf(x7 - M) * inv);
    *(uint4*)base = v0;
    *(uint4*)(base + 8) = v1;
    base += 4096;
  }
}

// ---------------------------------------------------------------------------
// G2: ctx partials = attn @ X. Pure gload16 staging for A and B (both packed
// linear). BK=64, K-split x2. grid (8 zz, 8 z, 8 nty) — zz (mt,s) FASTEST so
// the 4 mt-blocks sharing one B-slab are dispatch-adjacent.
// ---------------------------------------------------------------------------
__global__ __launch_bounds__(256) void gemm2p(
    const ushort* __restrict__ At, const ushort* __restrict__ Xp2,
    float* __restrict__ P) {
  __shared__ alignas(16) ushort sA[8192];
  __shared__ alignas(16) ushort sB[8192];
  const int mt = blockIdx.x & 3, s = blockIdx.x >> 2;
  const int z = blockIdx.y, nty = blockIdx.z;
  const int tid = threadIdx.x;
  const int wave = tid >> 6, lane = tid & 63;
  const int wm = wave >> 1, wn = wave & 1;
  const int fr = lane & 15, fq = lane >> 4;
  const int sfr = swz(fr);

  const ushort* Ab = At + (size_t)(z * 4 + mt) * 524288 + (size_t)s * 262144;
  const ushort* Bb = Xp2 + ((size_t)(z * 8 + nty) * 128 + s * 64) * 4096;

  f32x4 acc[4][4];
#pragma unroll
  for (int a = 0; a < 4; ++a)
#pragma unroll
    for (int c = 0; c < 4; ++c) acc[a][c] = (f32x4){0.f, 0.f, 0.f, 0.f};

  for (int it = 0; it < 32; ++it) {
#pragma unroll
    for (int j = 0; j < 4; ++j) {
      gload16(Bb + (size_t)it * 8192 + wave * 2048 + j * 512 + lane * 8,
              &sB[wave * 2048 + j * 512]);
      gload16(Ab + (size_t)it * 8192 + wave * 2048 + j * 512 + lane * 8,
              &sA[wave * 2048 + j * 512]);
    }
    __syncthreads();
#pragma unroll
    for (int kk = 0; kk < 2; ++kk) {
      bf16x8 aF[4], bF[4];
#pragma unroll
      for (int u = 0; u < 4; ++u) {
        aF[u] = *(const bf16x8*)&sA[kk * 4096 + ((wm << 6) + (u << 4) + fr) * 32 + ((fq ^ sfr) << 3)];
        bF[u] = *(const bf16x8*)&sB[kk * 4096 + ((wn << 6) + (u << 4) + fr) * 32 + ((fq ^ sfr) << 3)];
      }
#pragma unroll
      for (int mi = 0; mi < 4; ++mi)
#pragma unroll
        for (int ni = 0; ni < 4; ++ni)
          acc[mi][ni] = __builtin_amdgcn_mfma_f32_16x16x32_bf16(
              aF[mi], bF[ni], acc[mi][ni], 0, 0, 0);
    }
    __syncthreads();
  }

  float* Pb = P + (((size_t)(s * 8 + z) * 512) + mt * 128) * 1024 + nty * 128;
#pragma unroll
  for (int mi = 0; mi < 4; ++mi)
#pragma unroll
    for (int ni = 0; ni < 4; ++ni)
#pragma unroll
      for (int r = 0; r < 4; ++r) {
        const int row = (wm << 6) + (mi << 4) + (fq << 2) + r;
        const int col = (wn << 6) + (ni << 4) + fr;
        Pb[(size_t)row * 1024 + col] = acc[mi][ni][r];
      }
}

// ---------------------------------------------------------------------------
// ctxwv_gemm: folds P0+P1 sum into A-staging; per (ks,h,b) partial
// tmp2 = ctx @ Wv_h. -> P2 fp32 [4][256][1024].
// ---------------------------------------------------------------------------
__global__ __launch_bounds__(256) void ctxwv_gemm(
    const float* __restrict__ P, const ushort* __restrict__ WvT,
    float* __restrict__ P2) {
  __shared__ alignas(16) ushort sA[32 * 264];
  __shared__ alignas(16) ushort sB[64 * 264];
  const int ks = blockIdx.x, h = blockIdx.y, b = blockIdx.z;
  const int kb = ks << 8;
  const int t = threadIdx.x;
#pragma unroll
  for (int q = 0; q < 4; ++q) {
    const int i = t >> 3, seg = ((t & 7) + q * 8) << 3;
    const float* p0 = P + ((size_t)(0 * 8 + b) * 512 + h * 32 + i) * 1024 + kb + seg;
    const float* p1 = P + ((size_t)(1 * 8 + b) * 512 + h * 32 + i) * 1024 + kb + seg;
    const float4 a0 = *(const float4*)p0,       a1 = *(const float4*)(p0 + 4);
    const float4 b0 = *(const float4*)p1,       b1 = *(const float4*)(p1 + 4);
    uint4 o;
    o.x = packb(a0.x + b0.x, a0.y + b0.y);
    o.y = packb(a0.z + b0.z, a0.w + b0.w);
    o.z = packb(a1.x + b1.x, a1.y + b1.y);
    o.w = packb(a1.z + b1.z, a1.w + b1.w);
    *(uint4*)&sA[i * 264 + seg] = o;
  }
#pragma unroll
  for (int p = 0; p < 8; ++p) {
    const int rr = (t >> 3) + (p & 1) * 32;
    const int seg = ((t & 7) + (p >> 1) * 8) << 3;
    *(uint4*)&sB[rr * 264 + seg] =
        *(const uint4*)(WvT + (size_t)(h * 64 + rr) * 1024 + kb + seg);
  }
  __syncthreads();

  const int wave = t >> 6, lane = t & 63;
  const int fr = lane & 15, fq = lane >> 4;
  f32x4 acc[2];
  acc[0] = (f32x4){0.f, 0.f, 0.f, 0.f};
  acc[1] = (f32x4){0.f, 0.f, 0.f, 0.f};

#pragma unroll
  for (int ki = 0; ki < 8; ++ki) {
    bf16x8 bFr = *(const bf16x8*)&sB[((wave << 4) + fr) * 264 + (ki << 5) + (fq << 3)];
#pragma unroll
    for (int mi = 0; mi < 2; ++mi) {
      bf16x8 aF = *(const bf16x8*)&sA[((mi << 4) + fr) * 264 + (ki << 5) + (fq << 3)];
      acc[mi] = __builtin_amdgcn_mfma_f32_16x16x32_bf16(aF, bFr, acc[mi], 0, 0, 0);
    }
  }
  float* dst = P2 + (size_t)ks * 262144;
#pragma unroll
  for (int mi = 0; mi < 2; ++mi)
#pragma unroll
    for (int rr = 0; rr < 4; ++rr) {
      const int row = b * 32 + (mi << 4) + (fq << 2) + rr;
      const int col = h * 64 + (wave << 4) + fr;
      dst[(size_t)row * 1024 + col] = acc[mi][rr];
    }
}

// ---------------------------------------------------------------------------
// out_gemm: folds P2 4-way sum into A-staging; out partials = tmp2 @ Wo,
// K-split x4 -> O4 fp32. grid (8,2,4).
// ---------------------------------------------------------------------------
__global__ __launch_bounds__(256) void out_gemm(
    const float* __restrict__ P2, const ushort* __restrict__ WoT,
    float* __restrict__ O4) {
  __shared__ alignas(16) ushort sA[128 * 40];
  __shared__ alignas(16) ushort sB[128 * 40];
  const int nt = blockIdx.x, mt = blockIdx.y, ks = blockIdx.z;
  const int m0 = mt << 7, n0 = nt << 7, kb = ks << 8;
  const int t = threadIdx.x;
  const int wave = t >> 6, lane = t & 63;
  const int wm = wave >> 1, wn = wave & 1;
  const int fr = lane & 15, fq = lane >> 4;
  const int r = t >> 1, sg = (t & 1) << 4;

  f32x4 acc[4][4];
#pragma unroll
  for (int a = 0; a < 4; ++a)
#pragma unroll
    for (int c = 0; c < 4; ++c) acc[a][c] = (f32x4){0.f, 0.f, 0.f, 0.f};

  for (int it = 0; it < 8; ++it) {
    const int k0 = kb + (it << 5);
    {
      float s[16];
#pragma unroll
      for (int j = 0; j < 16; ++j) s[j] = 0.f;
#pragma unroll
      for (int p = 0; p < 4; ++p) {
        const float* base = P2 + (size_t)p * 262144 + (size_t)(m0 + r) * 1024 + k0 + sg;
#pragma unroll
        for (int q = 0; q < 4; ++q) {
          const float4 v = *(const float4*)(base + q * 4);
          s[q*4+0] += v.x; s[q*4+1] += v.y; s[q*4+2] += v.z; s[q*4+3] += v.w;
        }
      }
      uint4 o0, o1;
      o0.x = packb(s[0], s[1]);   o0.y = packb(s[2], s[3]);
      o0.z = packb(s[4], s[5]);   o0.w = packb(s[6], s[7]);
      o1.x = packb(s[8], s[9]);   o1.y = packb(s[10], s[11]);
      o1.z = packb(s[12], s[13]); o1.w = packb(s[14], s[15]);
      *(uint4*)&sA[r * 40 + sg]     = o0;
      *(uint4*)&sA[r * 40 + sg + 8] = o1;
    }
    {
      const uint4* s4 = (const uint4*)(WoT + (size_t)(n0 + r) * 1024 + k0 + sg);
      *(uint4*)&sB[r * 40 + sg]     = s4[0];
      *(uint4*)&sB[r * 40 + sg + 8] = s4[1];
    }
    __syncthreads();
    bf16x8 aF[4], bF[4];
#pragma unroll
    for (int u = 0; u < 4; ++u) {
      aF[u] = *(const bf16x8*)&sA[((wm << 6) + (u << 4) + fr) * 40 + (fq << 3)];
      bF[u] = *(const bf16x8*)&sB[((wn << 6) + (u << 4) + fr) * 40 + (fq << 3)];
    }
#pragma unroll
    for (int mi = 0; mi < 4; ++mi)
#pragma unroll
      for (int ni = 0; ni < 4; ++ni)
        acc[mi][ni] = __builtin_amdgcn_mfma_f32_16x16x32_bf16(
            aF[mi], bF[ni], acc[mi][ni], 0, 0, 0);
    __syncthreads();
  }
  float* dst = O4 + (size_t)ks * 262144;
#pragma unroll
  for (int mi = 0; mi < 4; ++mi)
#pragma unroll
    for (int ni = 0; ni < 4; ++ni)
#pragma unroll
      for (int rr = 0; rr < 4; ++rr) {
        const int row = m0 + (wm << 6) + (mi << 4) + (fq << 2) + rr;
        const int col = n0 + (wn << 6) + (ni << 4) + fr;
        dst[(size_t)row * 1024 + col] = acc[mi][ni][rr];
      }
}

// ---------------------------------------------------------------------------
__global__ __launch_bounds__(256) void sum_out4(
    const float* __restrict__ O4, float* __restrict__ out) {
  const size_t i4 = ((size_t)blockIdx.x * 256 + threadIdx.x) * 4;
  float4 acc = *(const float4*)(O4 + i4);
#pragma unroll
  for (int p = 1; p < 4; ++p) {
    const float4 v = *(const float4*)(O4 + (size_t)p * 262144 + i4);
    acc.x += v.x; acc.y += v.y; acc.z += v.z; acc.w += v.w;
  }
  *(float4*)(out + i4) = acc;
}

// ---------------------------------------------------------------------------
extern "C" void kernel_launch(void* const* d_in, const int* in_sizes, int n_in,
                              void* d_out, int out_size, void* d_ws, size_t ws_size,
                              hipStream_t stream) {
  const float* hs  = (const float*)d_in[0];
  const float* enc = (const float*)d_in[1];
  const int*   pos = (const int*)d_in[2];
  const float* Wq  = (const float*)d_in[3];
  const float* Wk  = (const float*)d_in[4];
  const float* Wv  = (const float*)d_in[5];
  const float* Wo  = (const float*)d_in[6];
  float* out = (float*)d_out;

  char* w = (char*)d_ws;
  ushort* Xp1  = (ushort*)w;               // gemm1 B (67 MB)
  float*  P    = (float*)w;                // ALIAS: gemm2p partials 33.5MB (Xp1 dead)
  w += (size_t)67108864;
  ushort* Xp2  = (ushort*)w;               // gemm2p B (67 MB)
  float*  P2   = (float*)w;                // ALIAS: ctxwv partials 4MB (Xp2 dead)
  w += (size_t)67108864;
  ushort* qk   = (ushort*)w; w += (size_t)8388608;    // [8][512][1024] bf16
  ushort* Sc   = (ushort*)w; w += (size_t)33554432;   // packed scores -> attn
  float2* pstat  = (float2*)w; w += (size_t)1048576;
  float*  qP   = (float*)w;                // [4][256][1024] fp32
  float*  O4   = (float*)w;                // ALIAS (qP dead after qk_rope_gemm)
  w += (size_t)4194304;
  ushort* WqT = (ushort*)w; w += (size_t)2097152;
  ushort* Wkb = (ushort*)w; w += (size_t)2097152;
  ushort* WvT = (ushort*)w; w += (size_t)2097152;
  ushort* WoT = (ushort*)w; w += (size_t)2097152;

  pack_all<<<dim3(16, 32, 10), 256, 0, stream>>>(enc, Xp1, Xp2,
      Wq, Wk, Wv, Wo, WqT, Wkb, WvT, WoT);
  qrope_gemm<<<dim3(8, 2, 4), 256, 0, stream>>>(hs, WqT, qP);
  qk_rope_gemm<<<dim3(4, 16, 8), 256, 0, stream>>>(qP, Wkb, pos, qk);
  gemm1<<<dim3(4, 8, 32), 256, 0, stream>>>(qk, Xp1, Sc, pstat);
  softmax_apply2<<<dim3(32, 16), 256, 0, stream>>>(Sc, pstat);
  gemm2p<<<dim3(8, 8, 8), 256, 0, stream>>>(Sc, Xp2, P);
  ctxwv_gemm<<<dim3(4, 16, 8), 256, 0, stream>>>(P, WvT, P2);
  out_gemm<<<dim3(8, 2, 4), 256, 0, stream>>>(P2, WoT, O4);
  sum_out4<<<256, 256, 0, stream>>>(O4, out);
}

// Round 8
// 418.804 us; speedup vs baseline: 1.0371x; 1.0371x over previous
//
#include <hip/hip_runtime.h>

// ---------------------------------------------------------------------------
// R13: (a) REVERT R12 grid permutes — old (z-fastest) order put all 4
// mt-repeats of each B-slab on the SAME XCD (i%8 = z%8); R12's mt-fastest
// spread them over 4 non-coherent L2s -> FETCH doubled (139MB = 2x B),
// gemm1 85->101 µs. (b) gemm1: alias sMx/sSm stats into sA (dead after
// K-loop) -> LDS 34816->32768 B -> 5 blocks/CU (+25% waves; gemm1 is
// latency-bound: MfmaUtil 13%, VALUBusy 22%, occ 21%).
// pack_all = R10 verbatim (84 µs best).
// ---------------------------------------------------------------------------

typedef float    f32x4  __attribute__((ext_vector_type(4)));
typedef __bf16   bf16x8 __attribute__((ext_vector_type(8)));
typedef unsigned u32x4  __attribute__((ext_vector_type(4)));

__device__ __forceinline__ ushort f2b(float x) {
  union { float f; unsigned u; } v; v.f = x;
  unsigned r = (v.u + 0x7fffu + ((v.u >> 16) & 1u)) >> 16;
  return (ushort)r;
}
__device__ __forceinline__ float b2f(ushort h) {
  union { unsigned u; float f; } v; v.u = ((unsigned)h) << 16; return v.f;
}
__device__ __forceinline__ void unpack2(unsigned v, float& lo, float& hi) {
  union { unsigned u; float f; } a, b;
  a.u = v << 16; b.u = v & 0xffff0000u;
  lo = a.f; hi = b.f;
}
__device__ __forceinline__ unsigned packb(float a, float b) {
  return (unsigned)f2b(a) | ((unsigned)f2b(b) << 16);
}
__device__ __forceinline__ int swz(int r) { return (r & 3) ^ ((r >> 2) & 3); }

__device__ __forceinline__ void gload16(const void* g, void* l) {
  __builtin_amdgcn_global_load_lds(
      (const __attribute__((address_space(1))) void*)g,
      (__attribute__((address_space(3))) void*)l, 16, 0, 0);
}

// ---------------------------------------------------------------------------
// pack_all: z<8 -> pack X tile into Xp1/Xp2 (R5 logic); z in {8,9} -> pack
// one 64x64 weight tile. grid (16, 32, 10), 256 thr. [R10 verbatim]
// ---------------------------------------------------------------------------
__global__ __launch_bounds__(256) void pack_all(
    const float* __restrict__ X, ushort* __restrict__ Xp1, ushort* __restrict__ Xp2,
    const float* __restrict__ Wq, const float* __restrict__ Wk,
    const float* __restrict__ Wv, const float* __restrict__ Wo,
    ushort* __restrict__ WqT, ushort* __restrict__ Wkb,
    ushort* __restrict__ WvT, ushort* __restrict__ WoT) {
  const int t = threadIdx.x;
  if (blockIdx.z < 8) {
    const int z = blockIdx.z, jb = blockIdx.y, cb = blockIdx.x;
    __shared__ ushort sT[128 * 72];
#pragma unroll
    for (int rep = 0; rep < 2; ++rep) {
      const int j  = rep * 64 + (t >> 2);
      const int c0 = (t & 3) << 4;
      const float4* src = (const float4*)(X + ((size_t)z * 4096 + jb * 128 + j) * 1024 + cb * 64 + c0);
#pragma unroll
      for (int q = 0; q < 4; ++q) {
        const float4 v = src[q];
        ushort4 w; w.x = f2b(v.x); w.y = f2b(v.y); w.z = f2b(v.z); w.w = f2b(v.w);
        *(ushort4*)&sT[j * 72 + c0 + q * 4] = w;
      }
    }
    __syncthreads();

    ushort* o1 = Xp1 + ((size_t)(z * 32 + jb) * 32 + cb * 2) * 4096;
#pragma unroll
    for (int q = 0; q < 4; ++q) {
      const int kih = q >> 1;
      const int r   = ((q & 1) << 6) + (t >> 2);
      const int p   = t & 3;
      const int lc  = p ^ swz(r);
      const u32x4 v = *(const u32x4*)&sT[r * 72 + kih * 32 + lc * 8];
      __builtin_nontemporal_store(
          v, (u32x4*)&o1[(size_t)kih * 4096 + ((size_t)(q & 1) << 11) + (size_t)t * 8]);
    }

    ushort* o2 = Xp2 + (((size_t)(z * 8 + (cb >> 1)) * 128 + jb * 4) * 4096) + ((size_t)(cb & 1) << 11);
#pragma unroll
    for (int q = 0; q < 4; ++q) {
      const int cl = t >> 2;
      const int p2 = t & 3;
      const int lj = p2 ^ swz(cl);
      union { ushort u[8]; u32x4 v; } pk;
#pragma unroll
      for (int jj = 0; jj < 8; ++jj) pk.u[jj] = sT[(q * 32 + lj * 8 + jj) * 72 + cl];
      __builtin_nontemporal_store(
          pk.v, (u32x4*)&o2[(size_t)q * 4096 + (size_t)t * 8]);
    }
  } else {
    const int wsel = (blockIdx.z - 8) * 2 + (blockIdx.y >> 4);
    const float* src = (wsel == 0) ? Wq : (wsel == 1) ? Wk : (wsel == 2) ? Wv : Wo;
    const int row0 = (blockIdx.y & 15) << 6, col0 = blockIdx.x << 6;
    __shared__ ushort sW[64 * 72];
    const int r = t >> 2, c0 = (t & 3) << 4;

    union { ushort u[16]; uint4 v[2]; } pk;
    const float4* s4 = (const float4*)(src + (size_t)(row0 + r) * 1024 + col0 + c0);
#pragma unroll
    for (int q = 0; q < 4; ++q) {
      const float4 v = s4[q];
      pk.u[q*4+0] = f2b(v.x); pk.u[q*4+1] = f2b(v.y);
      pk.u[q*4+2] = f2b(v.z); pk.u[q*4+3] = f2b(v.w);
    }
    if (wsel == 1) {
      ushort* dst = Wkb + (size_t)(row0 + r) * 1024 + col0 + c0;
      *(uint4*)dst = pk.v[0];
      *(uint4*)(dst + 8) = pk.v[1];
    } else {
#pragma unroll
      for (int q = 0; q < 16; ++q) sW[r * 72 + c0 + q] = pk.u[q];
      __syncthreads();
      ushort* dst = (wsel == 0) ? WqT : (wsel == 2) ? WvT : WoT;
      union { ushort u[16]; uint4 v[2]; } o;
#pragma unroll
      for (int q = 0; q < 16; ++q) o.u[q] = sW[(c0 + q) * 72 + r];
      ushort* d = dst + (size_t)(col0 + r) * 1024 + row0 + c0;
      *(uint4*)d = o.v[0];
      *(uint4*)(d + 8) = o.v[1];
    }
  }
}

// ---------------------------------------------------------------------------
// qrope_gemm: q = hs @ Wq, K-split x4 -> qP fp32 [4][256][1024]. grid (8,2,4).
// ---------------------------------------------------------------------------
__global__ __launch_bounds__(256) void qrope_gemm(
    const float* __restrict__ hs, const ushort* __restrict__ WqT,
    float* __restrict__ qP) {
  __shared__ alignas(16) ushort sA[128 * 40];
  __shared__ alignas(16) ushort sB[128 * 40];
  const int nt = blockIdx.x, mt = blockIdx.y, ks = blockIdx.z;
  const int m0 = mt << 7, n0 = nt << 7, kb = ks << 8;
  const int t = threadIdx.x;
  const int wave = t >> 6, lane = t & 63;
  const int wm = wave >> 1, wn = wave & 1;
  const int fr = lane & 15, fq = lane >> 4;
  const int r = t >> 1, sg = (t & 1) << 4;

  f32x4 acc[4][4];
#pragma unroll
  for (int a = 0; a < 4; ++a)
#pragma unroll
    for (int c = 0; c < 4; ++c) acc[a][c] = (f32x4){0.f, 0.f, 0.f, 0.f};

  for (int it = 0; it < 8; ++it) {
    const int k0 = kb + (it << 5);
    {
      const float4* s4 = (const float4*)(hs + (size_t)(m0 + r) * 1024 + k0 + sg);
      union { ushort u[16]; uint4 v[2]; } pk;
#pragma unroll
      for (int q = 0; q < 4; ++q) {
        const float4 v = s4[q];
        pk.u[q*4+0] = f2b(v.x); pk.u[q*4+1] = f2b(v.y);
        pk.u[q*4+2] = f2b(v.z); pk.u[q*4+3] = f2b(v.w);
      }
      *(uint4*)&sA[r * 40 + sg]     = pk.v[0];
      *(uint4*)&sA[r * 40 + sg + 8] = pk.v[1];
    }
    {
      const uint4* s4 = (const uint4*)(WqT + (size_t)(n0 + r) * 1024 + k0 + sg);
      *(uint4*)&sB[r * 40 + sg]     = s4[0];
      *(uint4*)&sB[r * 40 + sg + 8] = s4[1];
    }
    __syncthreads();
    bf16x8 aF[4], bF[4];
#pragma unroll
    for (int u = 0; u < 4; ++u) {
      aF[u] = *(const bf16x8*)&sA[((wm << 6) + (u << 4) + fr) * 40 + (fq << 3)];
      bF[u] = *(const bf16x8*)&sB[((wn << 6) + (u << 4) + fr) * 40 + (fq << 3)];
    }
#pragma unroll
    for (int mi = 0; mi < 4; ++mi)
#pragma unroll
      for (int ni = 0; ni < 4; ++ni)
        acc[mi][ni] = __builtin_amdgcn_mfma_f32_16x16x32_bf16(
            aF[mi], bF[ni], acc[mi][ni], 0, 0, 0);
    __syncthreads();
  }
  float* dst = qP + (size_t)ks * 262144;
#pragma unroll
  for (int mi = 0; mi < 4; ++mi)
#pragma unroll
    for (int ni = 0; ni < 4; ++ni)
#pragma unroll
      for (int rr = 0; rr < 4; ++rr) {
        const int row = m0 + (wm << 6) + (mi << 4) + (fq << 2) + rr;
        const int col = n0 + (wn << 6) + (ni << 4) + fr;
        dst[(size_t)row * 1024 + col] = acc[mi][ni][rr];
      }
}

// ---------------------------------------------------------------------------
// qk_rope_gemm: sA = bf16(RoPE(sum_ks qP)*0.125); qk = sA @ Wkb_head^T.
// grid (4 nc, 16 h, 8 b).
// ---------------------------------------------------------------------------
__global__ __launch_bounds__(256) void qk_rope_gemm(
    const float* __restrict__ qP, const ushort* __restrict__ Wkb,
    const int* __restrict__ pos, ushort* __restrict__ qk) {
  __shared__ float s_qf[32 * 68];
  __shared__ alignas(16) ushort sA[32 * 72];
  __shared__ alignas(16) ushort sB[256 * 72];
  const int nc = blockIdx.x, h = blockIdx.y, b = blockIdx.z;
  const int t = threadIdx.x;
  const int i = t >> 3, d0 = (t & 7) << 3;

  {
    float s[8];
#pragma unroll
    for (int j = 0; j < 8; ++j) s[j] = 0.f;
#pragma unroll
    for (int p = 0; p < 4; ++p) {
      const float* base = qP + (size_t)p * 262144 + (size_t)(b * 32 + i) * 1024 + h * 64 + d0;
      const float4 a0 = *(const float4*)base;
      const float4 a1 = *(const float4*)(base + 4);
      s[0]+=a0.x; s[1]+=a0.y; s[2]+=a0.z; s[3]+=a0.w;
      s[4]+=a1.x; s[5]+=a1.y; s[6]+=a1.z; s[7]+=a1.w;
    }
#pragma unroll
    for (int j = 0; j < 8; ++j) s_qf[i * 68 + d0 + j] = s[j];
  }
#pragma unroll
  for (int p = 0; p < 8; ++p) {
    const int rr = (t >> 3) + p * 32, seg = (t & 7) << 3;
    *(uint4*)&sB[rr * 72 + seg] =
        *(const uint4*)(Wkb + (size_t)(nc * 256 + rr) * 1024 + h * 64 + seg);
  }
  __syncthreads();

  {
    // int64 vs int32 layout probe: 16 odd slots suffice (P(all-zero|int32)~0)
    unsigned oddor = 0;
#pragma unroll
    for (int j = 1; j < 32; j += 2) oddor |= (unsigned)pos[j];
    const int m = b * 32 + i;
    const int p = (oddor == 0) ? pos[2 * m] : pos[m];
    const float pf = (float)p;
    union { ushort u16[8]; uint4 v; } o;
#pragma unroll
    for (int j = 0; j < 8; ++j) {
      const int d = d0 + j;
      const int f = d & 31;
      const float inv = powf(10000.0f, -(float)f * (1.0f / 32.0f));
      float sn, cs; sincosf(pf * inv, &sn, &cs);
      const float x  = s_qf[i * 68 + d];
      const float xp = s_qf[i * 68 + (d ^ 32)];
      const float v  = (d < 32) ? (x * cs - xp * sn) : (x * cs + xp * sn);
      o.u16[j] = f2b(v * 0.125f);
    }
    *(uint4*)&sA[i * 72 + d0] = o.v;
  }
  __syncthreads();

  const int wave = t >> 6, lane = t & 63;
  const int fr = lane & 15, fq = lane >> 4;
  f32x4 acc[2][4];
#pragma unroll
  for (int a = 0; a < 2; ++a)
#pragma unroll
    for (int c = 0; c < 4; ++c) acc[a][c] = (f32x4){0.f, 0.f, 0.f, 0.f};

#pragma unroll
  for (int ki = 0; ki < 2; ++ki) {
    bf16x8 aF[2], bF[4];
#pragma unroll
    for (int mi = 0; mi < 2; ++mi)
      aF[mi] = *(const bf16x8*)&sA[((mi << 4) + fr) * 72 + (ki << 5) + (fq << 3)];
#pragma unroll
    for (int ni = 0; ni < 4; ++ni)
      bF[ni] = *(const bf16x8*)&sB[((wave << 6) + (ni << 4) + fr) * 72 + (ki << 5) + (fq << 3)];
#pragma unroll
    for (int mi = 0; mi < 2; ++mi)
#pragma unroll
      for (int ni = 0; ni < 4; ++ni)
        acc[mi][ni] = __builtin_amdgcn_mfma_f32_16x16x32_bf16(
            aF[mi], bF[ni], acc[mi][ni], 0, 0, 0);
  }
#pragma unroll
  for (int mi = 0; mi < 2; ++mi)
#pragma unroll
    for (int ni = 0; ni < 4; ++ni)
#pragma unroll
      for (int rr = 0; rr < 4; ++rr) {
        const int row = h * 32 + (mi << 4) + (fq << 2) + rr;
        const int col = nc * 256 + (wave << 6) + (ni << 4) + fr;
        qk[((size_t)b * 512 + row) * 1024 + col] = f2b(acc[mi][ni][rr]);
      }
}

// ---------------------------------------------------------------------------
// G1: scores = qk @ X^T, BK=64. Packed Sc + per-row (max,sumexp) partials.
// grid (8 z, 32 nty, 4 mt) — REVERTED to R10 order (z fastest keeps all 4
// mt-repeats of a B-slab on one XCD: i%8 = z%8).
// Stats sMx/sSm ALIASED into sA (dead after K-loop) -> LDS 32768 B,
// 5 blocks/CU (exactly 160 KiB).
// ---------------------------------------------------------------------------
__global__ __launch_bounds__(256) void gemm1(
    const ushort* __restrict__ qk, const ushort* __restrict__ Xp1,
    ushort* __restrict__ Sc, float2* __restrict__ pstat) {
  __shared__ alignas(16) ushort sA[8192];
  __shared__ alignas(16) ushort sB[8192];
  // stats alias: sA is dead after the K-loop's final barrier.
  float* sMx = (float*)&sA[0];     // 256 floats = 1024 B
  float* sSm = (float*)&sA[512];   // next 1024 B
  const int z = blockIdx.x, nty = blockIdx.y, mt = blockIdx.z;
  const int tid = threadIdx.x;
  const int wave = tid >> 6, lane = tid & 63;
  const int wm = wave >> 1, wn = wave & 1;
  const int fr = lane & 15, fq = lane >> 4;
  const int sfr = swz(fr);

  const ushort* Ab = qk + ((size_t)z * 512 + mt * 128) * 1024;
  const ushort* Bb = Xp1 + ((size_t)(z * 32 + nty) * 32) * 4096;

  int arow[4], aoff[4];
#pragma unroll
  for (int j = 0; j < 4; ++j) {
    const int rowA = ((wave & 1) << 6) + (j << 4) + (lane >> 2);
    arow[j] = rowA;
    aoff[j] = ((wave >> 1) << 5) + (((lane & 3) ^ swz(rowA)) << 3);
  }

  f32x4 acc[4][4];
#pragma unroll
  for (int a = 0; a < 4; ++a)
#pragma unroll
    for (int c = 0; c < 4; ++c) acc[a][c] = (f32x4){0.f, 0.f, 0.f, 0.f};

  for (int it = 0; it < 16; ++it) {
    const int k0 = it << 6;
#pragma unroll
    for (int j = 0; j < 4; ++j) {
      gload16(Bb + (size_t)it * 8192 + wave * 2048 + j * 512 + lane * 8,
              &sB[wave * 2048 + j * 512]);
      gload16(Ab + (size_t)arow[j] * 1024 + k0 + aoff[j],
              &sA[wave * 2048 + j * 512]);
    }
    __syncthreads();
#pragma unroll
    for (int kk = 0; kk < 2; ++kk) {
      bf16x8 aF[4], bF[4];
#pragma unroll
      for (int u = 0; u < 4; ++u) {
        aF[u] = *(const bf16x8*)&sA[kk * 4096 + ((wm << 6) + (u << 4) + fr) * 32 + ((fq ^ sfr) << 3)];
        bF[u] = *(const bf16x8*)&sB[kk * 4096 + ((wn << 6) + (u << 4) + fr) * 32 + ((fq ^ sfr) << 3)];
      }
#pragma unroll
      for (int mi = 0; mi < 4; ++mi)
#pragma unroll
        for (int ni = 0; ni < 4; ++ni)
          acc[mi][ni] = __builtin_amdgcn_mfma_f32_16x16x32_bf16(
              aF[mi], bF[ni], acc[mi][ni], 0, 0, 0);
    }
    __syncthreads();
  }

  ushort* ScB = Sc + (size_t)(z * 4 + mt) * 524288;
#pragma unroll
  for (int mi = 0; mi < 4; ++mi)
#pragma unroll
    for (int ni = 0; ni < 4; ++ni)
#pragma unroll
      for (int r = 0; r < 4; ++r) {
        const int row = (wm << 6) + (mi << 4) + (fq << 2) + r;
        const int col = (wn << 6) + (ni << 4) + fr;
        const int ki  = (nty << 2) + (col >> 5);
        const int p   = ((col >> 3) & 3) ^ r ^ fq;
        const ushort hb = f2b(acc[mi][ni][r]);
        ScB[(size_t)ki * 4096 + row * 32 + p * 8 + (fr & 7)] = hb;
        acc[mi][ni][r] = b2f(hb);
      }

#pragma unroll
  for (int mi = 0; mi < 4; ++mi)
#pragma unroll
    for (int r = 0; r < 4; ++r) {
      float m4 = fmaxf(fmaxf(acc[mi][0][r], acc[mi][1][r]),
                       fmaxf(acc[mi][2][r], acc[mi][3][r]));
#pragma unroll
      for (int o = 1; o < 16; o <<= 1) m4 = fmaxf(m4, __shfl_xor(m4, o));
      float s4 = __expf(acc[mi][0][r] - m4) + __expf(acc[mi][1][r] - m4) +
                 __expf(acc[mi][2][r] - m4) + __expf(acc[mi][3][r] - m4);
#pragma unroll
      for (int o = 1; o < 16; o <<= 1) s4 += __shfl_xor(s4, o);
      if (fr == 0) {
        const int row = (wm << 6) + (mi << 4) + (fq << 2) + r;
        sMx[row * 2 + wn] = m4;
        sSm[row * 2 + wn] = s4;
      }
    }
  __syncthreads();
  if (tid < 128) {
    const float m0 = sMx[tid * 2], m1 = sMx[tid * 2 + 1];
    const float M = fmaxf(m0, m1);
    const float S = sSm[tid * 2] * __expf(m0 - M) + sSm[tid * 2 + 1] * __expf(m1 - M);
    pstat[((size_t)(z * 512 + mt * 128 + tid)) * 32 + nty] = make_float2(M, S);
  }
}

// ---------------------------------------------------------------------------
// softmax_apply2: combine stats (prologue) + apply exp in place on packed Sc.
// grid (32 zmt, 16 kg), 256 thr; each block: 8 ki-slabs of 8KB.
// ---------------------------------------------------------------------------
__global__ __launch_bounds__(256) void softmax_apply2(
    ushort* __restrict__ Sc, const float2* __restrict__ pstat) {
  __shared__ float sM[128], sI[128];
  const int zmt = blockIdx.x, kg = blockIdx.y;
  const int t = threadIdx.x;
  if (t < 128) {
    const float2* p = pstat + ((size_t)zmt * 128 + t) * 32;
    float M = -1e30f;
#pragma unroll
    for (int i = 0; i < 32; ++i) M = fmaxf(M, p[i].x);
    float S = 0.f;
#pragma unroll
    for (int i = 0; i < 32; ++i) S += p[i].y * __expf(p[i].x - M);
    sM[t] = M; sI[t] = 1.0f / S;
  }
  __syncthreads();
  const int r = t >> 1;
  const float M = sM[r], inv = sI[r];
  ushort* base = Sc + ((size_t)zmt * 128 + kg * 8) * 4096 + t * 16;
#pragma unroll
  for (int kt = 0; kt < 8; ++kt) {
    uint4 v0 = *(uint4*)base;
    uint4 v1 = *(uint4*)(base + 8);
    float x0,x1,x2,x3,x4,x5,x6,x7;
    unpack2(v0.x, x0, x1); unpack2(v0.y, x2, x3);
    unpack2(v0.z, x4, x5); unpack2(v0.w, x6, x7);
    v0.x = packb(__expf(x0 - M) * inv, __expf(x1 - M) * inv);
    v0.y = packb(__expf(x2 - M) * inv, __expf(x3 - M) * inv);
    v0.z = packb(__expf(x4 - M) * inv, __expf(x5 - M) * inv);
    v0.w = packb(__expf(x6 - M) * inv, __expf(x7 - M) * inv);
    unpack2(v1.x, x0, x1); unpack2(v1.y, x2, x3);
    unpack2(v1.z, x4, x5); unpack2(v1.w, x6, x7);
    v1.x = packb(__expf(x0 - M) * inv, __expf(x1 - M) * inv);
    v1.y = packb(__expf(x2 - M) * inv, __expf(x3 - M) * inv);
    v1.z = packb(__expf(x4 - M) * inv, __expf(x5 - M) * inv);
    v1.w = packb(__expf(x6 - M) * inv, __expf(x7 - M) * inv);
    *(uint4*)base = v0;
    *(uint4*)(base + 8) = v1;
    base += 4096;
  }
}

// ---------------------------------------------------------------------------
// G2: ctx partials = attn @ X. Pure gload16 staging for A and B (both packed
// linear). BK=64, K-split x2. grid (8 z, 8 nty, 4mt*2s) — REVERTED R10 order.
// ---------------------------------------------------------------------------
__global__ __launch_bounds__(256) void gemm2p(
    const ushort* __restrict__ At, const ushort* __restrict__ Xp2,
    float* __restrict__ P) {
  __shared__ alignas(16) ushort sA[8192];
  __shared__ alignas(16) ushort sB[8192];
  const int z = blockIdx.x, nty = blockIdx.y;
  const int mt = blockIdx.z & 3, s = blockIdx.z >> 2;
  const int tid = threadIdx.x;
  const int wave = tid >> 6, lane = tid & 63;
  const int wm = wave >> 1, wn = wave & 1;
  const int fr = lane & 15, fq = lane >> 4;
  const int sfr = swz(fr);

  const ushort* Ab = At + (size_t)(z * 4 + mt) * 524288 + (size_t)s * 262144;
  const ushort* Bb = Xp2 + ((size_t)(z * 8 + nty) * 128 + s * 64) * 4096;

  f32x4 acc[4][4];
#pragma unroll
  for (int a = 0; a < 4; ++a)
#pragma unroll
    for (int c = 0; c < 4; ++c) acc[a][c] = (f32x4){0.f, 0.f, 0.f, 0.f};

  for (int it = 0; it < 32; ++it) {
#pragma unroll
    for (int j = 0; j < 4; ++j) {
      gload16(Bb + (size_t)it * 8192 + wave * 2048 + j * 512 + lane * 8,
              &sB[wave * 2048 + j * 512]);
      gload16(Ab + (size_t)it * 8192 + wave * 2048 + j * 512 + lane * 8,
              &sA[wave * 2048 + j * 512]);
    }
    __syncthreads();
#pragma unroll
    for (int kk = 0; kk < 2; ++kk) {
      bf16x8 aF[4], bF[4];
#pragma unroll
      for (int u = 0; u < 4; ++u) {
        aF[u] = *(const bf16x8*)&sA[kk * 4096 + ((wm << 6) + (u << 4) + fr) * 32 + ((fq ^ sfr) << 3)];
        bF[u] = *(const bf16x8*)&sB[kk * 4096 + ((wn << 6) + (u << 4) + fr) * 32 + ((fq ^ sfr) << 3)];
      }
#pragma unroll
      for (int mi = 0; mi < 4; ++mi)
#pragma unroll
        for (int ni = 0; ni < 4; ++ni)
          acc[mi][ni] = __builtin_amdgcn_mfma_f32_16x16x32_bf16(
              aF[mi], bF[ni], acc[mi][ni], 0, 0, 0);
    }
    __syncthreads();
  }

  float* Pb = P + (((size_t)(s * 8 + z) * 512) + mt * 128) * 1024 + nty * 128;
#pragma unroll
  for (int mi = 0; mi < 4; ++mi)
#pragma unroll
    for (int ni = 0; ni < 4; ++ni)
#pragma unroll
      for (int r = 0; r < 4; ++r) {
        const int row = (wm << 6) + (mi << 4) + (fq << 2) + r;
        const int col = (wn << 6) + (ni << 4) + fr;
        Pb[(size_t)row * 1024 + col] = acc[mi][ni][r];
      }
}

// ---------------------------------------------------------------------------
// ctxwv_gemm: folds P0+P1 sum into A-staging; per (ks,h,b) partial
// tmp2 = ctx @ Wv_h. -> P2 fp32 [4][256][1024].
// ---------------------------------------------------------------------------
__global__ __launch_bounds__(256) void ctxwv_gemm(
    const float* __restrict__ P, const ushort* __restrict__ WvT,
    float* __restrict__ P2) {
  __shared__ alignas(16) ushort sA[32 * 264];
  __shared__ alignas(16) ushort sB[64 * 264];
  const int ks = blockIdx.x, h = blockIdx.y, b = blockIdx.z;
  const int kb = ks << 8;
  const int t = threadIdx.x;
#pragma unroll
  for (int q = 0; q < 4; ++q) {
    const int i = t >> 3, seg = ((t & 7) + q * 8) << 3;
    const float* p0 = P + ((size_t)(0 * 8 + b) * 512 + h * 32 + i) * 1024 + kb + seg;
    const float* p1 = P + ((size_t)(1 * 8 + b) * 512 + h * 32 + i) * 1024 + kb + seg;
    const float4 a0 = *(const float4*)p0,       a1 = *(const float4*)(p0 + 4);
    const float4 b0 = *(const float4*)p1,       b1 = *(const float4*)(p1 + 4);
    uint4 o;
    o.x = packb(a0.x + b0.x, a0.y + b0.y);
    o.y = packb(a0.z + b0.z, a0.w + b0.w);
    o.z = packb(a1.x + b1.x, a1.y + b1.y);
    o.w = packb(a1.z + b1.z, a1.w + b1.w);
    *(uint4*)&sA[i * 264 + seg] = o;
  }
#pragma unroll
  for (int p = 0; p < 8; ++p) {
    const int rr = (t >> 3) + (p & 1) * 32;
    const int seg = ((t & 7) + (p >> 1) * 8) << 3;
    *(uint4*)&sB[rr * 264 + seg] =
        *(const uint4*)(WvT + (size_t)(h * 64 + rr) * 1024 + kb + seg);
  }
  __syncthreads();

  const int wave = t >> 6, lane = t & 63;
  const int fr = lane & 15, fq = lane >> 4;
  f32x4 acc[2];
  acc[0] = (f32x4){0.f, 0.f, 0.f, 0.f};
  acc[1] = (f32x4){0.f, 0.f, 0.f, 0.f};

#pragma unroll
  for (int ki = 0; ki < 8; ++ki) {
    bf16x8 bFr = *(const bf16x8*)&sB[((wave << 4) + fr) * 264 + (ki << 5) + (fq << 3)];
#pragma unroll
    for (int mi = 0; mi < 2; ++mi) {
      bf16x8 aF = *(const bf16x8*)&sA[((mi << 4) + fr) * 264 + (ki << 5) + (fq << 3)];
      acc[mi] = __builtin_amdgcn_mfma_f32_16x16x32_bf16(aF, bFr, acc[mi], 0, 0, 0);
    }
  }
  float* dst = P2 + (size_t)ks * 262144;
#pragma unroll
  for (int mi = 0; mi < 2; ++mi)
#pragma unroll
    for (int rr = 0; rr < 4; ++rr) {
      const int row = b * 32 + (mi << 4) + (fq << 2) + rr;
      const int col = h * 64 + (wave << 4) + fr;
      dst[(size_t)row * 1024 + col] = acc[mi][rr];
    }
}

// ---------------------------------------------------------------------------
// out_gemm: folds P2 4-way sum into A-staging; out partials = tmp2 @ Wo,
// K-split x4 -> O4 fp32. grid (8,2,4).
// ---------------------------------------------------------------------------
__global__ __launch_bounds__(256) void out_gemm(
    const float* __restrict__ P2, const ushort* __restrict__ WoT,
    float* __restrict__ O4) {
  __shared__ alignas(16) ushort sA[128 * 40];
  __shared__ alignas(16) ushort sB[128 * 40];
  const int nt = blockIdx.x, mt = blockIdx.y, ks = blockIdx.z;
  const int m0 = mt << 7, n0 = nt << 7, kb = ks << 8;
  const int t = threadIdx.x;
  const int wave = t >> 6, lane = t & 63;
  const int wm = wave >> 1, wn = wave & 1;
  const int fr = lane & 15, fq = lane >> 4;
  const int r = t >> 1, sg = (t & 1) << 4;

  f32x4 acc[4][4];
#pragma unroll
  for (int a = 0; a < 4; ++a)
#pragma unroll
    for (int c = 0; c < 4; ++c) acc[a][c] = (f32x4){0.f, 0.f, 0.f, 0.f};

  for (int it = 0; it < 8; ++it) {
    const int k0 = kb + (it << 5);
    {
      float s[16];
#pragma unroll
      for (int j = 0; j < 16; ++j) s[j] = 0.f;
#pragma unroll
      for (int p = 0; p < 4; ++p) {
        const float* base = P2 + (size_t)p * 262144 + (size_t)(m0 + r) * 1024 + k0 + sg;
#pragma unroll
        for (int q = 0; q < 4; ++q) {
          const float4 v = *(const float4*)(base + q * 4);
          s[q*4+0] += v.x; s[q*4+1] += v.y; s[q*4+2] += v.z; s[q*4+3] += v.w;
        }
      }
      uint4 o0, o1;
      o0.x = packb(s[0], s[1]);   o0.y = packb(s[2], s[3]);
      o0.z = packb(s[4], s[5]);   o0.w = packb(s[6], s[7]);
      o1.x = packb(s[8], s[9]);   o1.y = packb(s[10], s[11]);
      o1.z = packb(s[12], s[13]); o1.w = packb(s[14], s[15]);
      *(uint4*)&sA[r * 40 + sg]     = o0;
      *(uint4*)&sA[r * 40 + sg + 8] = o1;
    }
    {
      const uint4* s4 = (const uint4*)(WoT + (size_t)(n0 + r) * 1024 + k0 + sg);
      *(uint4*)&sB[r * 40 + sg]     = s4[0];
      *(uint4*)&sB[r * 40 + sg + 8] = s4[1];
    }
    __syncthreads();
    bf16x8 aF[4], bF[4];
#pragma unroll
    for (int u = 0; u < 4; ++u) {
      aF[u] = *(const bf16x8*)&sA[((wm << 6) + (u << 4) + fr) * 40 + (fq << 3)];
      bF[u] = *(const bf16x8*)&sB[((wn << 6) + (u << 4) + fr) * 40 + (fq << 3)];
    }
#pragma unroll
    for (int mi = 0; mi < 4; ++mi)
#pragma unroll
      for (int ni = 0; ni < 4; ++ni)
        acc[mi][ni] = __builtin_amdgcn_mfma_f32_16x16x32_bf16(
            aF[mi], bF[ni], acc[mi][ni], 0, 0, 0);
    __syncthreads();
  }
  float* dst = O4 + (size_t)ks * 262144;
#pragma unroll
  for (int mi = 0; mi < 4; ++mi)
#pragma unroll
    for (int ni = 0; ni < 4; ++ni)
#pragma unroll
      for (int rr = 0; rr < 4; ++rr) {
        const int row = m0 + (wm << 6) + (mi << 4) + (fq << 2) + rr;
        const int col = n0 + (wn << 6) + (ni << 4) + fr;
        dst[(size_t)row * 1024 + col] = acc[mi][ni][rr];
      }
}

// ---------------------------------------------------------------------------
__global__ __launch_bounds__(256) void sum_out4(
    const float* __restrict__ O4, float* __restrict__ out) {
  const size_t i4 = ((size_t)blockIdx.x * 256 + threadIdx.x) * 4;
  float4 acc = *(const float4*)(O4 + i4);
#pragma unroll
  for (int p = 1; p < 4; ++p) {
    const float4 v = *(const float4*)(O4 + (size_t)p * 262144 + i4);
    acc.x += v.x; acc.y += v.y; acc.z += v.z; acc.w += v.w;
  }
  *(float4*)(out + i4) = acc;
}

// ---------------------------------------------------------------------------
extern "C" void kernel_launch(void* const* d_in, const int* in_sizes, int n_in,
                              void* d_out, int out_size, void* d_ws, size_t ws_size,
                              hipStream_t stream) {
  const float* hs  = (const float*)d_in[0];
  const float* enc = (const float*)d_in[1];
  const int*   pos = (const int*)d_in[2];
  const float* Wq  = (const float*)d_in[3];
  const float* Wk  = (const float*)d_in[4];
  const float* Wv  = (const float*)d_in[5];
  const float* Wo  = (const float*)d_in[6];
  float* out = (float*)d_out;

  char* w = (char*)d_ws;
  ushort* Xp1  = (ushort*)w;               // gemm1 B (67 MB)
  float*  P    = (float*)w;                // ALIAS: gemm2p partials 33.5MB (Xp1 dead)
  w += (size_t)67108864;
  ushort* Xp2  = (ushort*)w;               // gemm2p B (67 MB)
  float*  P2   = (float*)w;                // ALIAS: ctxwv partials 4MB (Xp2 dead)
  w += (size_t)67108864;
  ushort* qk   = (ushort*)w; w += (size_t)8388608;    // [8][512][1024] bf16
  ushort* Sc   = (ushort*)w; w += (size_t)33554432;   // packed scores -> attn
  float2* pstat  = (float2*)w; w += (size_t)1048576;
  float*  qP   = (float*)w;                // [4][256][1024] fp32
  float*  O4   = (float*)w;                // ALIAS (qP dead after qk_rope_gemm)
  w += (size_t)4194304;
  ushort* WqT = (ushort*)w; w += (size_t)2097152;
  ushort* Wkb = (ushort*)w; w += (size_t)2097152;
  ushort* WvT = (ushort*)w; w += (size_t)2097152;
  ushort* WoT = (ushort*)w; w += (size_t)2097152;

  pack_all<<<dim3(16, 32, 10), 256, 0, stream>>>(enc, Xp1, Xp2,
      Wq, Wk, Wv, Wo, WqT, Wkb, WvT, WoT);
  qrope_gemm<<<dim3(8, 2, 4), 256, 0, stream>>>(hs, WqT, qP);
  qk_rope_gemm<<<dim3(4, 16, 8), 256, 0, stream>>>(qP, Wkb, pos, qk);
  gemm1<<<dim3(8, 32, 4), 256, 0, stream>>>(qk, Xp1, Sc, pstat);
  softmax_apply2<<<dim3(32, 16), 256, 0, stream>>>(Sc, pstat);
  gemm2p<<<dim3(8, 8, 8), 256, 0, stream>>>(Sc, Xp2, P);
  ctxwv_gemm<<<dim3(4, 16, 8), 256, 0, stream>>>(P, WvT, P2);
  out_gemm<<<dim3(8, 2, 4), 256, 0, stream>>>(P2, WoT, O4);
  sum_out4<<<256, 256, 0, stream>>>(O4, out);
}